// Round 12
// baseline (704.347 us; speedup 1.0000x reference)
//
#include <hip/hip_runtime.h>

// GlobalEdgeGnn on MI355X (gfx950) — round 11.
// Changes vs round 10 (conv-occupancy round):
//  1. k_conv: DROP the R6 hoisted 16-load staging (never A/B'd; forces ~128 VGPR ->
//     4 blocks/CU). Per-kb inline gathers (pre-R6 style, 68 VGPR measured) and
//     __launch_bounds__(256,6) -> 24 waves/CU. Compiler schedules the loads.
//  2. k_edge: (256,6)->(256,8) (VGPR_Count=40 fits 8 blocks/CU).
//  3. xsI/xs0/xs1/xs2 are contiguous in ws: one merged memset (saves 3 launches).
// Everything else identical to round 10 (693.6us).

#define NN 50000
#define NE 500000
#define DE 1000000   // 2E directed
#define NEB 7813     // k_init / k_edge grid blocks

typedef __attribute__((ext_vector_type(8))) __bf16 bfrag;
typedef __attribute__((ext_vector_type(8))) short  svec8;
typedef __attribute__((ext_vector_type(4))) float  f32x4;

__device__ __forceinline__ unsigned short f2bf(float f){
  unsigned u = __builtin_bit_cast(unsigned, f);
  u += 0x7fffu + ((u >> 16) & 1u);          // RNE
  return (unsigned short)(u >> 16);
}
__device__ __forceinline__ float bf2f(unsigned short s){
  return __builtin_bit_cast(float, ((unsigned)s) << 16);
}
#define MFMA __builtin_amdgcn_mfma_f32_16x16x32_bf16

__device__ __forceinline__ bfrag hbuild2(svec8 pv, svec8 qv){
  bfrag r;
  #pragma unroll
  for (int i = 0; i < 8; i++){
    float f = bf2f((unsigned short)pv[i]) + bf2f((unsigned short)qv[i]);
    f = f > 0.f ? f : 0.f;
    r[i] = (__bf16)f;
  }
  return r;
}

// ---------------- CSR build ----------------
__global__ void k_hist(const int* __restrict__ ei, int* __restrict__ cnt,
                       int* __restrict__ cnt2){
  int e = blockIdx.x*256 + threadIdx.x;
  if (e >= DE) return;
  int dst = (e < NE) ? ei[NE + e] : ei[e - NE];   // bi_dst
  atomicAdd(&cnt[dst], 1);
  if (e < NE) atomicAdd(&cnt2[ei[e]], 1);         // src histogram
}

__device__ __forceinline__ void scan_impl(const int* __restrict__ cnt,
                                          int* __restrict__ off, int* __restrict__ cur,
                                          float* __restrict__ dinv, int total){
  __shared__ int wsum[16];
  __shared__ int carry_s;
  int tid = threadIdx.x;
  int lane = tid & 63, w = tid >> 6;
  int carry = 0;
  for (int base = 0; base < NN; base += 1024){
    int idx = base + tid;
    int v = (idx < NN) ? cnt[idx] : 0;
    int inc = v;
    for (int o2 = 1; o2 < 64; o2 <<= 1){
      int t = __shfl_up(inc, o2);
      if (lane >= o2) inc += t;
    }
    if (lane == 63) wsum[w] = inc;
    __syncthreads();
    if (tid < 16){
      int vv = wsum[tid], p = vv;
      for (int o2 = 1; o2 < 16; o2 <<= 1){
        int t = __shfl_up(p, o2, 16);
        if (tid >= o2) p += t;
      }
      wsum[tid] = p - vv;
    }
    __syncthreads();
    int ex = carry + wsum[w] + inc - v;
    if (idx < NN){
      off[idx] = ex; cur[idx] = ex;
      dinv[idx] = 1.0f / (float)(v > 1 ? v : 1);
    }
    if (tid == 1023) carry_s = carry + wsum[15] + inc;
    __syncthreads();
    carry = carry_s;
  }
  if (tid == 0) off[NN] = total;
}

__global__ void k_scan2(const int* __restrict__ cntA, int* __restrict__ offA,
                        int* __restrict__ curA, float* __restrict__ dinvA,
                        const int* __restrict__ cntB, int* __restrict__ offB,
                        int* __restrict__ curB, float* __restrict__ dinvB){
  if (blockIdx.x == 0) scan_impl(cntA, offA, curA, dinvA, DE);
  else                 scan_impl(cntB, offB, curB, dinvB, NE);
}

__global__ void k_fill(const int* __restrict__ ei, int* __restrict__ cur,
                       int* __restrict__ nbr, int* __restrict__ dstA, int* __restrict__ eid,
                       int* __restrict__ cur2, int* __restrict__ eord,
                       int* __restrict__ es, int* __restrict__ ed){
  int e = blockIdx.x*256 + threadIdx.x;
  if (e >= DE) return;
  int s, d, id;
  if (e < NE){ s = ei[e];  d = ei[NE + e]; id = e;      }
  else       { s = ei[e];  d = ei[e - NE]; id = e - NE; }
  int pos = atomicAdd(&cur[d], 1);
  nbr[pos] = s; dstA[pos] = d; eid[pos] = id;
  if (e < NE){
    int p2 = atomicAdd(&cur2[s], 1);
    eord[p2] = e; es[p2] = s; ed[p2] = d;
  }
}

// ---------------- weight pack to MFMA B-fragment order (bf16) ----------------
__global__ void k_pack(const float* __restrict__ nw1, const float* __restrict__ nw2,
                       const float* __restrict__ ew1, const float* __restrict__ ew2,
                       unsigned short* __restrict__ wp){
  int t = blockIdx.x*256 + threadIdx.x;
  if (t >= 98304) return;
  const float* src; int NO, p, base;
  if (t < 49152)      { int l = t/16384;            src = nw1 + l*16384; NO=128; p = t - l*16384;      base = t - p; }
  else if (t < 73728) { int q = t-49152; int l=q/8192; src = nw2 + l*8192; NO=64; p = q - l*8192;      base = t - p; }
  else if (t < 90112) {                              src = ew1;           NO=128; p = t - 73728;       base = 73728; }
  else                {                              src = ew2;           NO=64;  p = t - 90112;       base = 90112; }
  int f = p >> 9, r = p & 511, lane = r >> 3, i = r & 7;
  int NB = NO >> 4, kb = f / NB, nb = f - kb*NB;
  int k = kb*32 + ((lane >> 4) << 3) + i;
  int c = nb*16 + (lane & 15);
  wp[base + p] = f2bf(src[k*NO + c]);
}

// ---------------- node init: edge-slot-parallel gather + segmented reduce ----------------
__global__ __launch_bounds__(256,6) void k_init(
    const float* __restrict__ ef, const int* __restrict__ dstA,
    const int* __restrict__ eid, float* __restrict__ xsum)
{
  int lane = threadIdx.x & 63, wid = threadIdx.x >> 6;
  int tile = (blockIdx.x*4 + wid) * 32;
  if (tile >= DE) return;
  int q = lane >> 4, c4 = lane & 15;
  int dr = dstA[tile + (lane & 31)];
  int er = eid[tile + (lane & 31)];
  f32x4 v[8];
  #pragma unroll
  for (int it = 0; it < 8; it++){
    int row = q + it*4;
    int e = __shfl(er, row);
    v[it] = *(const f32x4*)(ef + (size_t)e*64 + c4*4);
  }
  int prev = __shfl_up(dr, 1);
  bool flag = (lane < 32) && (lane == 0 || dr != prev);
  unsigned long long mask = __ballot(flag);
  while (mask){
    int s = (int)__builtin_ctzll(mask);
    mask &= mask - 1;
    int e = mask ? (int)__builtin_ctzll(mask) : 32;
    int dseg = __shfl(dr, s);
    f32x4 p = {0,0,0,0};
    #pragma unroll
    for (int it = 0; it < 8; it++){
      int row = q + it*4;
      if ((unsigned)(row - s) < (unsigned)(e - s)) p += v[it];
    }
    #pragma unroll
    for (int k = 0; k < 4; k++){
      p[k] += __shfl_xor(p[k], 16);
      p[k] += __shfl_xor(p[k], 32);
    }
    if (q == 0){
      atomicAdd(&xsum[dseg*64 + c4*4 + 0], p[0]);
      atomicAdd(&xsum[dseg*64 + c4*4 + 1], p[1]);
      atomicAdd(&xsum[dseg*64 + c4*4 + 2], p[2]);
      atomicAdd(&xsum[dseg*64 + c4*4 + 3], p[3]);
    }
  }
}

// ---------------- fused x-update + P/Q producer ----------------
__global__ __launch_bounds__(256,3) void k_pq(
    float* __restrict__ x, const float* __restrict__ xs, const float* __restrict__ dinv,
    int mode,
    const unsigned short* __restrict__ wp, int w1off,
    const float* __restrict__ bias,
    unsigned short* __restrict__ pq)
{
  int lane = threadIdx.x & 63, wid = threadIdx.x >> 6;
  int tile = (blockIdx.x*4 + wid) * 32;
  if (tile >= NN) return;
  int r16 = lane & 15, g = lane >> 4;
  const svec8* w1g = (const svec8*)(wp + w1off);
  bfrag a[2][2];
  #pragma unroll
  for (int rb = 0; rb < 2; rb++){
    int n0 = tile + rb*16 + r16;
    bool vrow = n0 < NN;
    int n = vrow ? n0 : NN-1;
    float dv = dinv[n];
    #pragma unroll
    for (int kb = 0; kb < 2; kb++){
      size_t base = (size_t)n*64 + kb*32 + g*8;
      f32x4 sa = *(const f32x4*)(xs + base);
      f32x4 sb = *(const f32x4*)(xs + base + 4);
      f32x4 xa = {0,0,0,0}, xb = {0,0,0,0};
      if (mode){ xa = *(const f32x4*)(x + base); xb = *(const f32x4*)(x + base + 4); }
      f32x4 na = xa + sa*dv;
      f32x4 nb_ = xb + sb*dv;
      if (vrow){
        *(f32x4*)(x + base) = na;
        *(f32x4*)(x + base + 4) = nb_;
      }
      bfrag av;
      #pragma unroll
      for (int i = 0; i < 4; i++){ av[i] = (__bf16)na[i]; av[4+i] = (__bf16)nb_[i]; }
      a[rb][kb] = av;
    }
  }
  for (int ph = 0; ph < 2; ph++){
    f32x4 acc[8][2];
    #pragma unroll
    for (int nb = 0; nb < 8; nb++){ acc[nb][0] = (f32x4){0,0,0,0}; acc[nb][1] = (f32x4){0,0,0,0}; }
    #pragma unroll
    for (int kb = 0; kb < 2; kb++){
      #pragma unroll
      for (int nb = 0; nb < 8; nb++){
        bfrag b = __builtin_bit_cast(bfrag, w1g[((ph*2+kb)*8+nb)*64 + lane]);
        acc[nb][0] = MFMA(a[0][kb], b, acc[nb][0], 0, 0, 0);
        acc[nb][1] = MFMA(a[1][kb], b, acc[nb][1], 0, 0, 0);
      }
    }
    int half = ph ? 128 : 0;
    #pragma unroll
    for (int nb = 0; nb < 8; nb++){
      float bv = (ph == 0) ? bias[nb*16 + r16] : 0.f;
      #pragma unroll
      for (int rb = 0; rb < 2; rb++){
        #pragma unroll
        for (int j = 0; j < 4; j++){
          int n = tile + rb*16 + g*4 + j;
          if (n < NN) pq[(size_t)n*256 + half + nb*16 + r16] = f2bf(acc[nb][rb][j] + bv);
        }
      }
    }
  }
}

// ---------------- NodeConv: one tile/wave, per-kb inline gathers, occ 6 ----------------
__global__ __launch_bounds__(256,6) void k_conv(
    const unsigned short* __restrict__ pq,
    const int* __restrict__ cdst, const int* __restrict__ cnbr,
    const unsigned short* __restrict__ wp, int w2off,
    const float* __restrict__ b2, float* __restrict__ xsum)
{
  int lane = threadIdx.x & 63, wid = threadIdx.x >> 6;
  int tile = (blockIdx.x*4 + wid) * 32;
  if (tile >= DE) return;
  int r16 = lane & 15, g = lane >> 4;
  int dr = cdst[tile + (lane & 31)];
  int d0 = cdst[tile + r16],      d1 = cdst[tile + 16 + r16];
  int s0 = cnbr[tile + r16],      s1 = cnbr[tile + 16 + r16];
  const svec8* w2g = (const svec8*)(wp + w2off);

  f32x4 acc[4][2];
  #pragma unroll
  for (int nb = 0; nb < 4; nb++){ acc[nb][0] = (f32x4){0,0,0,0}; acc[nb][1] = (f32x4){0,0,0,0}; }

  #pragma unroll
  for (int kb = 0; kb < 4; kb++){
    int off = kb*32 + g*8;
    bfrag h0 = hbuild2(*(const svec8*)(pq + (size_t)d0*256 + off),
                       *(const svec8*)(pq + (size_t)s0*256 + 128 + off));
    bfrag h1 = hbuild2(*(const svec8*)(pq + (size_t)d1*256 + off),
                       *(const svec8*)(pq + (size_t)s1*256 + 128 + off));
    #pragma unroll
    for (int nb = 0; nb < 4; nb++){
      bfrag b = __builtin_bit_cast(bfrag, w2g[(kb*4+nb)*64 + lane]);
      acc[nb][0] = MFMA(h0, b, acc[nb][0], 0, 0, 0);
      acc[nb][1] = MFMA(h1, b, acc[nb][1], 0, 0, 0);
    }
  }
  float m[4][2][4];
  #pragma unroll
  for (int nb = 0; nb < 4; nb++){
    float bv = b2[nb*16 + r16];
    #pragma unroll
    for (int rb = 0; rb < 2; rb++){
      #pragma unroll
      for (int j = 0; j < 4; j++){
        float v = acc[nb][rb][j] + bv;
        m[nb][rb][j] = v > 0.f ? v : 0.f;
      }
    }
  }
  int prev = __shfl_up(dr, 1);
  bool flag = (lane < 32) && (lane == 0 || dr != prev);
  unsigned long long mask = __ballot(flag);
  while (mask){
    int s = (int)__builtin_ctzll(mask);
    mask &= mask - 1;
    int e = mask ? (int)__builtin_ctzll(mask) : 32;
    int dseg = __shfl(dr, s);
    float p0 = 0.f, p1 = 0.f, p2 = 0.f, p3 = 0.f;
    #pragma unroll
    for (int rb = 0; rb < 2; rb++){
      #pragma unroll
      for (int j = 0; j < 4; j++){
        int row = rb*16 + g*4 + j;
        if ((unsigned)(row - s) < (unsigned)(e - s)){
          p0 += m[0][rb][j]; p1 += m[1][rb][j]; p2 += m[2][rb][j]; p3 += m[3][rb][j];
        }
      }
    }
    p0 += __shfl_xor(p0, 16); p0 += __shfl_xor(p0, 32);
    p1 += __shfl_xor(p1, 16); p1 += __shfl_xor(p1, 32);
    p2 += __shfl_xor(p2, 16); p2 += __shfl_xor(p2, 32);
    p3 += __shfl_xor(p3, 16); p3 += __shfl_xor(p3, 32);
    if (g == 0){
      atomicAdd(&xsum[dseg*64 +      r16], p0);
      atomicAdd(&xsum[dseg*64 + 16 + r16], p1);
      atomicAdd(&xsum[dseg*64 + 32 + r16], p2);
      atomicAdd(&xsum[dseg*64 + 48 + r16], p3);
    }
  }
}

// ---------------- symmetric edge MLP: src-sorted, occ 8 ----------------
__global__ __launch_bounds__(256,8) void k_edge(
    const unsigned short* __restrict__ pq,
    const int* __restrict__ eord, const int* __restrict__ es, const int* __restrict__ ed,
    const unsigned short* __restrict__ wp,
    const float* __restrict__ b2,
    float* __restrict__ outp, float* __restrict__ part)
{
  __shared__ float wred[4];
  int lane = threadIdx.x & 63, wid = threadIdx.x >> 6;
  int tile = (blockIdx.x*4 + wid) * 16;
  bool valid = tile < NE;
  int tl = valid ? tile : 0;
  int r16 = lane & 15, g = lane >> 4;
  const svec8* w2g = (const svec8*)(wp + 90112);
  int eidv = eord[tl + r16];
  int sid  = es[tl + r16], did = ed[tl + r16];

  f32x4 acc[4][2];
  #pragma unroll
  for (int nb = 0; nb < 4; nb++){ acc[nb][0] = (f32x4){0,0,0,0}; acc[nb][1] = (f32x4){0,0,0,0}; }

  #pragma unroll
  for (int kb = 0; kb < 4; kb++){
    int off = kb*32 + g*8;
    bfrag h0 = hbuild2(*(const svec8*)(pq + (size_t)sid*256 + off),
                       *(const svec8*)(pq + (size_t)did*256 + 128 + off));  // e1
    bfrag h1 = hbuild2(*(const svec8*)(pq + (size_t)did*256 + off),
                       *(const svec8*)(pq + (size_t)sid*256 + 128 + off));  // e2
    #pragma unroll
    for (int nb = 0; nb < 4; nb++){
      bfrag b = __builtin_bit_cast(bfrag, w2g[(kb*4+nb)*64 + lane]);
      acc[nb][0] = MFMA(h0, b, acc[nb][0], 0, 0, 0);
      acc[nb][1] = MFMA(h1, b, acc[nb][1], 0, 0, 0);
    }
  }
  float lsum = 0.f;
  #pragma unroll
  for (int nb = 0; nb < 4; nb++){
    float bv = b2[nb*16 + r16];
    #pragma unroll
    for (int j = 0; j < 4; j++){
      float v1 = acc[nb][0][j] + bv;
      float v2 = acc[nb][1][j] + bv;
      int eo = __shfl(eidv, g*4 + j);
      if (valid) outp[(size_t)eo*64 + nb*16 + r16] = 0.5f*(v1 + v2);
      float d = v1 - v2; lsum += d*d;
    }
  }
  if (!valid) lsum = 0.f;
  for (int o2 = 32; o2 > 0; o2 >>= 1) lsum += __shfl_down(lsum, o2);
  if (lane == 0) wred[wid] = lsum;
  __syncthreads();
  if (threadIdx.x == 0) part[blockIdx.x] = wred[0] + wred[1] + wred[2] + wred[3];
}

// ---------------- final loss reduction ----------------
__global__ void k_final(const float* __restrict__ part, float* __restrict__ outp){
  __shared__ float wred[16];
  int tid = threadIdx.x;
  float s = 0.f;
  for (int i = tid; i < NEB; i += 1024) s += part[i];
  for (int o2 = 32; o2 > 0; o2 >>= 1) s += __shfl_down(s, o2);
  int lane = tid & 63, w = tid >> 6;
  if (lane == 0) wred[w] = s;
  __syncthreads();
  if (tid == 0){
    float t = 0.f;
    #pragma unroll
    for (int i = 0; i < 16; i++) t += wred[i];
    outp[32000000] = t * (1.0f / 32000000.0f);
  }
}

// ---------------- launch ----------------
extern "C" void kernel_launch(void* const* d_in, const int* in_sizes, int n_in,
                              void* d_out, int out_size, void* d_ws, size_t ws_size,
                              hipStream_t stream)
{
  const float* ef  = (const float*)d_in[0];
  const int*   ei  = (const int*)  d_in[1];
  const float* nw1 = (const float*)d_in[2];
  const float* nb1 = (const float*)d_in[3];
  const float* nw2 = (const float*)d_in[4];
  const float* nb2 = (const float*)d_in[5];
  const float* ew1 = (const float*)d_in[6];
  const float* eb1 = (const float*)d_in[7];
  const float* ew2 = (const float*)d_in[8];
  const float* eb2 = (const float*)d_in[9];
  float* outp = (float*)d_out;

  char* ws = (char*)d_ws;
  size_t o = 0;
  auto alloc = [&](size_t b)->char*{ char* p = ws + o; o += (b + 255) & ~(size_t)255; return p; };
  int*   cnt  = (int*)  alloc((size_t)NN*4);
  int*   off  = (int*)  alloc((size_t)(NN+1)*4);
  int*   cur  = (int*)  alloc((size_t)NN*4);
  float* dinv = (float*)alloc((size_t)NN*4);
  int*   cnt2 = (int*)  alloc((size_t)NN*4);
  int*   off2 = (int*)  alloc((size_t)(NN+1)*4);
  int*   cur2 = (int*)  alloc((size_t)NN*4);
  float* dinvS= (float*)alloc((size_t)NN*4);
  int*   nbr  = (int*)  alloc((size_t)DE*4);
  int*   dstA = (int*)  alloc((size_t)DE*4);
  int*   eid  = (int*)  alloc((size_t)DE*4);
  int*   eord = (int*)  alloc((size_t)NE*4);
  int*   es   = (int*)  alloc((size_t)NE*4);
  int*   ed   = (int*)  alloc((size_t)NE*4);
  float* x    = (float*)alloc((size_t)NN*64*4);
  unsigned short* wp  = (unsigned short*)alloc((size_t)98304*2);
  float* part = (float*)alloc((size_t)NEB*4);
  unsigned short* pq  = (unsigned short*)alloc((size_t)NN*256*2);
  float* xsI  = (float*)alloc((size_t)NN*64*4);   // xsI/xs0/xs1/xs2 contiguous:
  float* xs0  = (float*)alloc((size_t)NN*64*4);   // sizes are 256B-multiples, so
  float* xs1  = (float*)alloc((size_t)NN*64*4);   // one merged memset covers all 4
  float* xs2  = (float*)alloc((size_t)NN*64*4);

  hipMemsetAsync(cnt,  0, (size_t)NN*4, stream);
  hipMemsetAsync(cnt2, 0, (size_t)NN*4, stream);
  hipMemsetAsync(xsI,  0, (size_t)NN*64*4*4, stream);   // merged: xsI..xs2
  k_hist<<<(DE+255)/256, 256, 0, stream>>>(ei, cnt, cnt2);
  k_scan2<<<2, 1024, 0, stream>>>(cnt, off, cur, dinv, cnt2, off2, cur2, dinvS);
  k_fill<<<(DE+255)/256, 256, 0, stream>>>(ei, cur, nbr, dstA, eid, cur2, eord, es, ed);
  k_pack<<<384, 256, 0, stream>>>(nw1, nw2, ew1, ew2, wp);
  k_init<<<NEB, 256, 0, stream>>>(ef, dstA, eid, xsI);
  k_pq<<<391, 256, 0, stream>>>(x, xsI, dinv, 0, wp, 0*16384, nb1 + 0*128, pq);
  k_conv<<<DE/128 + 1, 256, 0, stream>>>(pq, dstA, nbr, wp, 49152 + 0*8192, nb2 + 0*64, xs0);
  k_pq<<<391, 256, 0, stream>>>(x, xs0, dinv, 1, wp, 1*16384, nb1 + 1*128, pq);
  k_conv<<<DE/128 + 1, 256, 0, stream>>>(pq, dstA, nbr, wp, 49152 + 1*8192, nb2 + 1*64, xs1);
  k_pq<<<391, 256, 0, stream>>>(x, xs1, dinv, 1, wp, 2*16384, nb1 + 2*128, pq);
  k_conv<<<DE/128 + 1, 256, 0, stream>>>(pq, dstA, nbr, wp, 49152 + 2*8192, nb2 + 2*64, xs2);
  k_pq<<<391, 256, 0, stream>>>(x, xs2, dinv, 1, wp, 73728, eb1, pq);
  k_edge<<<NEB, 256, 0, stream>>>(pq, eord, es, ed, wp, eb2, outp, part);
  k_final<<<1, 1024, 0, stream>>>(part, outp);
}

// Round 13
// 686.379 us; speedup vs baseline: 1.0262x; 1.0262x over previous
//
#include <hip/hip_runtime.h>

// GlobalEdgeGnn on MI355X (gfx950) — round 12.
// Restore the best measured configuration (R10, 693.6us):
//   k_edge  __launch_bounds__(256,6)  [occ sweep 38/55/78% -> 93.4/90.8/100us: 55% optimal;
//                                      higher occ widens L2 src-window -> FETCH 132->169MB]
//   k_conv  hoisted staging, (256,4)  [inline-occ6 A/B'd neutral in R11]
//   k_init  (256,6), k_pq (256,3)
// Keep from R11: merged xsI..xs2 memset (3 fewer launches, noise-level).
// All hot kernels are at the random-gather service ceiling (~3 TB/s effective) on a
// 25.6MB pq table vs 4MB/XCD L2; occupancy insensitive both directions.

#define NN 50000
#define NE 500000
#define DE 1000000   // 2E directed
#define NEB 7813     // k_init / k_edge grid blocks

typedef __attribute__((ext_vector_type(8))) __bf16 bfrag;
typedef __attribute__((ext_vector_type(8))) short  svec8;
typedef __attribute__((ext_vector_type(4))) float  f32x4;

__device__ __forceinline__ unsigned short f2bf(float f){
  unsigned u = __builtin_bit_cast(unsigned, f);
  u += 0x7fffu + ((u >> 16) & 1u);          // RNE
  return (unsigned short)(u >> 16);
}
__device__ __forceinline__ float bf2f(unsigned short s){
  return __builtin_bit_cast(float, ((unsigned)s) << 16);
}
#define MFMA __builtin_amdgcn_mfma_f32_16x16x32_bf16

__device__ __forceinline__ bfrag hbuild2(svec8 pv, svec8 qv){
  bfrag r;
  #pragma unroll
  for (int i = 0; i < 8; i++){
    float f = bf2f((unsigned short)pv[i]) + bf2f((unsigned short)qv[i]);
    f = f > 0.f ? f : 0.f;
    r[i] = (__bf16)f;
  }
  return r;
}

// ---------------- CSR build ----------------
__global__ void k_hist(const int* __restrict__ ei, int* __restrict__ cnt,
                       int* __restrict__ cnt2){
  int e = blockIdx.x*256 + threadIdx.x;
  if (e >= DE) return;
  int dst = (e < NE) ? ei[NE + e] : ei[e - NE];   // bi_dst
  atomicAdd(&cnt[dst], 1);
  if (e < NE) atomicAdd(&cnt2[ei[e]], 1);         // src histogram
}

__device__ __forceinline__ void scan_impl(const int* __restrict__ cnt,
                                          int* __restrict__ off, int* __restrict__ cur,
                                          float* __restrict__ dinv, int total){
  __shared__ int wsum[16];
  __shared__ int carry_s;
  int tid = threadIdx.x;
  int lane = tid & 63, w = tid >> 6;
  int carry = 0;
  for (int base = 0; base < NN; base += 1024){
    int idx = base + tid;
    int v = (idx < NN) ? cnt[idx] : 0;
    int inc = v;
    for (int o2 = 1; o2 < 64; o2 <<= 1){
      int t = __shfl_up(inc, o2);
      if (lane >= o2) inc += t;
    }
    if (lane == 63) wsum[w] = inc;
    __syncthreads();
    if (tid < 16){
      int vv = wsum[tid], p = vv;
      for (int o2 = 1; o2 < 16; o2 <<= 1){
        int t = __shfl_up(p, o2, 16);
        if (tid >= o2) p += t;
      }
      wsum[tid] = p - vv;
    }
    __syncthreads();
    int ex = carry + wsum[w] + inc - v;
    if (idx < NN){
      off[idx] = ex; cur[idx] = ex;
      dinv[idx] = 1.0f / (float)(v > 1 ? v : 1);
    }
    if (tid == 1023) carry_s = carry + wsum[15] + inc;
    __syncthreads();
    carry = carry_s;
  }
  if (tid == 0) off[NN] = total;
}

__global__ void k_scan2(const int* __restrict__ cntA, int* __restrict__ offA,
                        int* __restrict__ curA, float* __restrict__ dinvA,
                        const int* __restrict__ cntB, int* __restrict__ offB,
                        int* __restrict__ curB, float* __restrict__ dinvB){
  if (blockIdx.x == 0) scan_impl(cntA, offA, curA, dinvA, DE);
  else                 scan_impl(cntB, offB, curB, dinvB, NE);
}

__global__ void k_fill(const int* __restrict__ ei, int* __restrict__ cur,
                       int* __restrict__ nbr, int* __restrict__ dstA, int* __restrict__ eid,
                       int* __restrict__ cur2, int* __restrict__ eord,
                       int* __restrict__ es, int* __restrict__ ed){
  int e = blockIdx.x*256 + threadIdx.x;
  if (e >= DE) return;
  int s, d, id;
  if (e < NE){ s = ei[e];  d = ei[NE + e]; id = e;      }
  else       { s = ei[e];  d = ei[e - NE]; id = e - NE; }
  int pos = atomicAdd(&cur[d], 1);
  nbr[pos] = s; dstA[pos] = d; eid[pos] = id;
  if (e < NE){
    int p2 = atomicAdd(&cur2[s], 1);
    eord[p2] = e; es[p2] = s; ed[p2] = d;
  }
}

// ---------------- weight pack to MFMA B-fragment order (bf16) ----------------
__global__ void k_pack(const float* __restrict__ nw1, const float* __restrict__ nw2,
                       const float* __restrict__ ew1, const float* __restrict__ ew2,
                       unsigned short* __restrict__ wp){
  int t = blockIdx.x*256 + threadIdx.x;
  if (t >= 98304) return;
  const float* src; int NO, p, base;
  if (t < 49152)      { int l = t/16384;            src = nw1 + l*16384; NO=128; p = t - l*16384;      base = t - p; }
  else if (t < 73728) { int q = t-49152; int l=q/8192; src = nw2 + l*8192; NO=64; p = q - l*8192;      base = t - p; }
  else if (t < 90112) {                              src = ew1;           NO=128; p = t - 73728;       base = 73728; }
  else                {                              src = ew2;           NO=64;  p = t - 90112;       base = 90112; }
  int f = p >> 9, r = p & 511, lane = r >> 3, i = r & 7;
  int NB = NO >> 4, kb = f / NB, nb = f - kb*NB;
  int k = kb*32 + ((lane >> 4) << 3) + i;
  int c = nb*16 + (lane & 15);
  wp[base + p] = f2bf(src[k*NO + c]);
}

// ---------------- node init: edge-slot-parallel gather + segmented reduce ----------------
__global__ __launch_bounds__(256,6) void k_init(
    const float* __restrict__ ef, const int* __restrict__ dstA,
    const int* __restrict__ eid, float* __restrict__ xsum)
{
  int lane = threadIdx.x & 63, wid = threadIdx.x >> 6;
  int tile = (blockIdx.x*4 + wid) * 32;
  if (tile >= DE) return;
  int q = lane >> 4, c4 = lane & 15;
  int dr = dstA[tile + (lane & 31)];
  int er = eid[tile + (lane & 31)];
  f32x4 v[8];
  #pragma unroll
  for (int it = 0; it < 8; it++){
    int row = q + it*4;
    int e = __shfl(er, row);
    v[it] = *(const f32x4*)(ef + (size_t)e*64 + c4*4);
  }
  int prev = __shfl_up(dr, 1);
  bool flag = (lane < 32) && (lane == 0 || dr != prev);
  unsigned long long mask = __ballot(flag);
  while (mask){
    int s = (int)__builtin_ctzll(mask);
    mask &= mask - 1;
    int e = mask ? (int)__builtin_ctzll(mask) : 32;
    int dseg = __shfl(dr, s);
    f32x4 p = {0,0,0,0};
    #pragma unroll
    for (int it = 0; it < 8; it++){
      int row = q + it*4;
      if ((unsigned)(row - s) < (unsigned)(e - s)) p += v[it];
    }
    #pragma unroll
    for (int k = 0; k < 4; k++){
      p[k] += __shfl_xor(p[k], 16);
      p[k] += __shfl_xor(p[k], 32);
    }
    if (q == 0){
      atomicAdd(&xsum[dseg*64 + c4*4 + 0], p[0]);
      atomicAdd(&xsum[dseg*64 + c4*4 + 1], p[1]);
      atomicAdd(&xsum[dseg*64 + c4*4 + 2], p[2]);
      atomicAdd(&xsum[dseg*64 + c4*4 + 3], p[3]);
    }
  }
}

// ---------------- fused x-update + P/Q producer ----------------
__global__ __launch_bounds__(256,3) void k_pq(
    float* __restrict__ x, const float* __restrict__ xs, const float* __restrict__ dinv,
    int mode,
    const unsigned short* __restrict__ wp, int w1off,
    const float* __restrict__ bias,
    unsigned short* __restrict__ pq)
{
  int lane = threadIdx.x & 63, wid = threadIdx.x >> 6;
  int tile = (blockIdx.x*4 + wid) * 32;
  if (tile >= NN) return;
  int r16 = lane & 15, g = lane >> 4;
  const svec8* w1g = (const svec8*)(wp + w1off);
  bfrag a[2][2];
  #pragma unroll
  for (int rb = 0; rb < 2; rb++){
    int n0 = tile + rb*16 + r16;
    bool vrow = n0 < NN;
    int n = vrow ? n0 : NN-1;
    float dv = dinv[n];
    #pragma unroll
    for (int kb = 0; kb < 2; kb++){
      size_t base = (size_t)n*64 + kb*32 + g*8;
      f32x4 sa = *(const f32x4*)(xs + base);
      f32x4 sb = *(const f32x4*)(xs + base + 4);
      f32x4 xa = {0,0,0,0}, xb = {0,0,0,0};
      if (mode){ xa = *(const f32x4*)(x + base); xb = *(const f32x4*)(x + base + 4); }
      f32x4 na = xa + sa*dv;
      f32x4 nb_ = xb + sb*dv;
      if (vrow){
        *(f32x4*)(x + base) = na;
        *(f32x4*)(x + base + 4) = nb_;
      }
      bfrag av;
      #pragma unroll
      for (int i = 0; i < 4; i++){ av[i] = (__bf16)na[i]; av[4+i] = (__bf16)nb_[i]; }
      a[rb][kb] = av;
    }
  }
  for (int ph = 0; ph < 2; ph++){
    f32x4 acc[8][2];
    #pragma unroll
    for (int nb = 0; nb < 8; nb++){ acc[nb][0] = (f32x4){0,0,0,0}; acc[nb][1] = (f32x4){0,0,0,0}; }
    #pragma unroll
    for (int kb = 0; kb < 2; kb++){
      #pragma unroll
      for (int nb = 0; nb < 8; nb++){
        bfrag b = __builtin_bit_cast(bfrag, w1g[((ph*2+kb)*8+nb)*64 + lane]);
        acc[nb][0] = MFMA(a[0][kb], b, acc[nb][0], 0, 0, 0);
        acc[nb][1] = MFMA(a[1][kb], b, acc[nb][1], 0, 0, 0);
      }
    }
    int half = ph ? 128 : 0;
    #pragma unroll
    for (int nb = 0; nb < 8; nb++){
      float bv = (ph == 0) ? bias[nb*16 + r16] : 0.f;
      #pragma unroll
      for (int rb = 0; rb < 2; rb++){
        #pragma unroll
        for (int j = 0; j < 4; j++){
          int n = tile + rb*16 + g*4 + j;
          if (n < NN) pq[(size_t)n*256 + half + nb*16 + r16] = f2bf(acc[nb][rb][j] + bv);
        }
      }
    }
  }
}

// ---------------- NodeConv (R10 config): one tile/wave, hoisted gathers, occ 4 ----------------
__global__ __launch_bounds__(256,4) void k_conv(
    const unsigned short* __restrict__ pq,
    const int* __restrict__ cdst, const int* __restrict__ cnbr,
    const unsigned short* __restrict__ wp, int w2off,
    const float* __restrict__ b2, float* __restrict__ xsum)
{
  int lane = threadIdx.x & 63, wid = threadIdx.x >> 6;
  int tile = (blockIdx.x*4 + wid) * 32;
  if (tile >= DE) return;
  int r16 = lane & 15, g = lane >> 4;
  int dr = cdst[tile + (lane & 31)];
  int d0 = cdst[tile + r16],      d1 = cdst[tile + 16 + r16];
  int s0 = cnbr[tile + r16],      s1 = cnbr[tile + 16 + r16];
  const svec8* w2g = (const svec8*)(wp + w2off);

  svec8 LP0[4], LQ0[4], LP1[4], LQ1[4];
  #pragma unroll
  for (int kb = 0; kb < 4; kb++){
    int off = kb*32 + g*8;
    LP0[kb] = *(const svec8*)(pq + (size_t)d0*256 + off);
    LQ0[kb] = *(const svec8*)(pq + (size_t)s0*256 + 128 + off);
    LP1[kb] = *(const svec8*)(pq + (size_t)d1*256 + off);
    LQ1[kb] = *(const svec8*)(pq + (size_t)s1*256 + 128 + off);
  }

  f32x4 acc[4][2];
  #pragma unroll
  for (int nb = 0; nb < 4; nb++){ acc[nb][0] = (f32x4){0,0,0,0}; acc[nb][1] = (f32x4){0,0,0,0}; }

  #pragma unroll
  for (int kb = 0; kb < 4; kb++){
    bfrag h0 = hbuild2(LP0[kb], LQ0[kb]);
    bfrag h1 = hbuild2(LP1[kb], LQ1[kb]);
    #pragma unroll
    for (int nb = 0; nb < 4; nb++){
      bfrag b = __builtin_bit_cast(bfrag, w2g[(kb*4+nb)*64 + lane]);
      acc[nb][0] = MFMA(h0, b, acc[nb][0], 0, 0, 0);
      acc[nb][1] = MFMA(h1, b, acc[nb][1], 0, 0, 0);
    }
  }
  float m[4][2][4];
  #pragma unroll
  for (int nb = 0; nb < 4; nb++){
    float bv = b2[nb*16 + r16];
    #pragma unroll
    for (int rb = 0; rb < 2; rb++){
      #pragma unroll
      for (int j = 0; j < 4; j++){
        float v = acc[nb][rb][j] + bv;
        m[nb][rb][j] = v > 0.f ? v : 0.f;
      }
    }
  }
  int prev = __shfl_up(dr, 1);
  bool flag = (lane < 32) && (lane == 0 || dr != prev);
  unsigned long long mask = __ballot(flag);
  while (mask){
    int s = (int)__builtin_ctzll(mask);
    mask &= mask - 1;
    int e = mask ? (int)__builtin_ctzll(mask) : 32;
    int dseg = __shfl(dr, s);
    float p0 = 0.f, p1 = 0.f, p2 = 0.f, p3 = 0.f;
    #pragma unroll
    for (int rb = 0; rb < 2; rb++){
      #pragma unroll
      for (int j = 0; j < 4; j++){
        int row = rb*16 + g*4 + j;
        if ((unsigned)(row - s) < (unsigned)(e - s)){
          p0 += m[0][rb][j]; p1 += m[1][rb][j]; p2 += m[2][rb][j]; p3 += m[3][rb][j];
        }
      }
    }
    p0 += __shfl_xor(p0, 16); p0 += __shfl_xor(p0, 32);
    p1 += __shfl_xor(p1, 16); p1 += __shfl_xor(p1, 32);
    p2 += __shfl_xor(p2, 16); p2 += __shfl_xor(p2, 32);
    p3 += __shfl_xor(p3, 16); p3 += __shfl_xor(p3, 32);
    if (g == 0){
      atomicAdd(&xsum[dseg*64 +      r16], p0);
      atomicAdd(&xsum[dseg*64 + 16 + r16], p1);
      atomicAdd(&xsum[dseg*64 + 32 + r16], p2);
      atomicAdd(&xsum[dseg*64 + 48 + r16], p3);
    }
  }
}

// ---------------- symmetric edge MLP (R10 config): src-sorted, occ 6 ----------------
__global__ __launch_bounds__(256,6) void k_edge(
    const unsigned short* __restrict__ pq,
    const int* __restrict__ eord, const int* __restrict__ es, const int* __restrict__ ed,
    const unsigned short* __restrict__ wp,
    const float* __restrict__ b2,
    float* __restrict__ outp, float* __restrict__ part)
{
  __shared__ float wred[4];
  int lane = threadIdx.x & 63, wid = threadIdx.x >> 6;
  int tile = (blockIdx.x*4 + wid) * 16;
  bool valid = tile < NE;
  int tl = valid ? tile : 0;
  int r16 = lane & 15, g = lane >> 4;
  const svec8* w2g = (const svec8*)(wp + 90112);
  int eidv = eord[tl + r16];
  int sid  = es[tl + r16], did = ed[tl + r16];

  svec8 SP[4], SQ[4], DP[4], DQ[4];
  #pragma unroll
  for (int kb = 0; kb < 4; kb++){
    int off = kb*32 + g*8;
    SP[kb] = *(const svec8*)(pq + (size_t)sid*256 + off);
    SQ[kb] = *(const svec8*)(pq + (size_t)sid*256 + 128 + off);
    DP[kb] = *(const svec8*)(pq + (size_t)did*256 + off);
    DQ[kb] = *(const svec8*)(pq + (size_t)did*256 + 128 + off);
  }

  f32x4 acc[4][2];
  #pragma unroll
  for (int nb = 0; nb < 4; nb++){ acc[nb][0] = (f32x4){0,0,0,0}; acc[nb][1] = (f32x4){0,0,0,0}; }

  #pragma unroll
  for (int kb = 0; kb < 4; kb++){
    bfrag h0 = hbuild2(SP[kb], DQ[kb]);   // e1 = emlp(x_src, x_dst)
    bfrag h1 = hbuild2(DP[kb], SQ[kb]);   // e2 = emlp(x_dst, x_src)
    #pragma unroll
    for (int nb = 0; nb < 4; nb++){
      bfrag b = __builtin_bit_cast(bfrag, w2g[(kb*4+nb)*64 + lane]);
      acc[nb][0] = MFMA(h0, b, acc[nb][0], 0, 0, 0);
      acc[nb][1] = MFMA(h1, b, acc[nb][1], 0, 0, 0);
    }
  }
  float lsum = 0.f;
  #pragma unroll
  for (int nb = 0; nb < 4; nb++){
    float bv = b2[nb*16 + r16];
    #pragma unroll
    for (int j = 0; j < 4; j++){
      float v1 = acc[nb][0][j] + bv;
      float v2 = acc[nb][1][j] + bv;
      int eo = __shfl(eidv, g*4 + j);
      if (valid) outp[(size_t)eo*64 + nb*16 + r16] = 0.5f*(v1 + v2);
      float d = v1 - v2; lsum += d*d;
    }
  }
  if (!valid) lsum = 0.f;
  for (int o2 = 32; o2 > 0; o2 >>= 1) lsum += __shfl_down(lsum, o2);
  if (lane == 0) wred[wid] = lsum;
  __syncthreads();
  if (threadIdx.x == 0) part[blockIdx.x] = wred[0] + wred[1] + wred[2] + wred[3];
}

// ---------------- final loss reduction ----------------
__global__ void k_final(const float* __restrict__ part, float* __restrict__ outp){
  __shared__ float wred[16];
  int tid = threadIdx.x;
  float s = 0.f;
  for (int i = tid; i < NEB; i += 1024) s += part[i];
  for (int o2 = 32; o2 > 0; o2 >>= 1) s += __shfl_down(s, o2);
  int lane = tid & 63, w = tid >> 6;
  if (lane == 0) wred[w] = s;
  __syncthreads();
  if (tid == 0){
    float t = 0.f;
    #pragma unroll
    for (int i = 0; i < 16; i++) t += wred[i];
    outp[32000000] = t * (1.0f / 32000000.0f);
  }
}

// ---------------- launch ----------------
extern "C" void kernel_launch(void* const* d_in, const int* in_sizes, int n_in,
                              void* d_out, int out_size, void* d_ws, size_t ws_size,
                              hipStream_t stream)
{
  const float* ef  = (const float*)d_in[0];
  const int*   ei  = (const int*)  d_in[1];
  const float* nw1 = (const float*)d_in[2];
  const float* nb1 = (const float*)d_in[3];
  const float* nw2 = (const float*)d_in[4];
  const float* nb2 = (const float*)d_in[5];
  const float* ew1 = (const float*)d_in[6];
  const float* eb1 = (const float*)d_in[7];
  const float* ew2 = (const float*)d_in[8];
  const float* eb2 = (const float*)d_in[9];
  float* outp = (float*)d_out;

  char* ws = (char*)d_ws;
  size_t o = 0;
  auto alloc = [&](size_t b)->char*{ char* p = ws + o; o += (b + 255) & ~(size_t)255; return p; };
  int*   cnt  = (int*)  alloc((size_t)NN*4);
  int*   off  = (int*)  alloc((size_t)(NN+1)*4);
  int*   cur  = (int*)  alloc((size_t)NN*4);
  float* dinv = (float*)alloc((size_t)NN*4);
  int*   cnt2 = (int*)  alloc((size_t)NN*4);
  int*   off2 = (int*)  alloc((size_t)(NN+1)*4);
  int*   cur2 = (int*)  alloc((size_t)NN*4);
  float* dinvS= (float*)alloc((size_t)NN*4);
  int*   nbr  = (int*)  alloc((size_t)DE*4);
  int*   dstA = (int*)  alloc((size_t)DE*4);
  int*   eid  = (int*)  alloc((size_t)DE*4);
  int*   eord = (int*)  alloc((size_t)NE*4);
  int*   es   = (int*)  alloc((size_t)NE*4);
  int*   ed   = (int*)  alloc((size_t)NE*4);
  float* x    = (float*)alloc((size_t)NN*64*4);
  unsigned short* wp  = (unsigned short*)alloc((size_t)98304*2);
  float* part = (float*)alloc((size_t)NEB*4);
  unsigned short* pq  = (unsigned short*)alloc((size_t)NN*256*2);
  float* xsI  = (float*)alloc((size_t)NN*64*4);   // xsI..xs2 contiguous (one memset)
  float* xs0  = (float*)alloc((size_t)NN*64*4);
  float* xs1  = (float*)alloc((size_t)NN*64*4);
  float* xs2  = (float*)alloc((size_t)NN*64*4);

  hipMemsetAsync(cnt,  0, (size_t)NN*4, stream);
  hipMemsetAsync(cnt2, 0, (size_t)NN*4, stream);
  hipMemsetAsync(xsI,  0, (size_t)NN*64*4*4, stream);   // merged: xsI..xs2
  k_hist<<<(DE+255)/256, 256, 0, stream>>>(ei, cnt, cnt2);
  k_scan2<<<2, 1024, 0, stream>>>(cnt, off, cur, dinv, cnt2, off2, cur2, dinvS);
  k_fill<<<(DE+255)/256, 256, 0, stream>>>(ei, cur, nbr, dstA, eid, cur2, eord, es, ed);
  k_pack<<<384, 256, 0, stream>>>(nw1, nw2, ew1, ew2, wp);
  k_init<<<NEB, 256, 0, stream>>>(ef, dstA, eid, xsI);
  k_pq<<<391, 256, 0, stream>>>(x, xsI, dinv, 0, wp, 0*16384, nb1 + 0*128, pq);
  k_conv<<<DE/128 + 1, 256, 0, stream>>>(pq, dstA, nbr, wp, 49152 + 0*8192, nb2 + 0*64, xs0);
  k_pq<<<391, 256, 0, stream>>>(x, xs0, dinv, 1, wp, 1*16384, nb1 + 1*128, pq);
  k_conv<<<DE/128 + 1, 256, 0, stream>>>(pq, dstA, nbr, wp, 49152 + 1*8192, nb2 + 1*64, xs1);
  k_pq<<<391, 256, 0, stream>>>(x, xs1, dinv, 1, wp, 2*16384, nb1 + 2*128, pq);
  k_conv<<<DE/128 + 1, 256, 0, stream>>>(pq, dstA, nbr, wp, 49152 + 2*8192, nb2 + 2*64, xs2);
  k_pq<<<391, 256, 0, stream>>>(x, xs2, dinv, 1, wp, 73728, eb1, pq);
  k_edge<<<NEB, 256, 0, stream>>>(pq, eord, es, ed, wp, eb2, outp, part);
  k_final<<<1, 1024, 0, stream>>>(part, outp);
}